// Round 14
// baseline (8741.044 us; speedup 1.0000x reference)
//
#include <hip/hip_runtime.h>

#define BSZ 256
#define TSZ 256
#define SSZ 64
#define ASZ 16
#define HSZ 512

typedef float f32x4 __attribute__((ext_vector_type(4)));
typedef short bf16x8 __attribute__((ext_vector_type(8)));
typedef unsigned short u16x8 __attribute__((ext_vector_type(8)));
typedef unsigned long long u64;
typedef unsigned short ushort_t;

// ---------------- workspace layout ----------------
#define XBUF_BYTES ((size_t)4 * BSZ * SSZ * sizeof(u64))              // 512KB
#define CNT_BYTES  ((size_t)16 * TSZ * sizeof(unsigned))              // 16KB
#define WT_ELEMS   ((size_t)4096 * 512)                               // per comp
#define WA1_ELEMS  ((size_t)64 * 512)                                 // per comp
#define WS_NEEDED  (XBUF_BYTES + CNT_BYTES + 3 * WT_ELEMS * sizeof(ushort_t) \
                    + 3 * WA1_ELEMS * sizeof(ushort_t))               // ~12.7MB

// Tiled W layout (per comp): elem = tile*16384 + kk*1024 + slot*256 + col*8 + e
// Tiled Wa1 layout (per comp): elem = ((ht*2+kk)*4 + slot)*256 + col*8 + e

// ---------------- MFMA ssm LDS layout (bytes) ----------------
#define XSTR        68                       // padded x row stride (floats)
#define MF_X_OFF    0                        // 16*68*4 = 4352 (pad to 4608)
#define MF_RED_OFF  4608                     // [8][16] f32 = 512
#define MF_HAH_OFF  5120                     // tiled ha: kk*1184+slot*288+s*16+e*2
#define MF_HAM_OFF  (5120 + 18944)           // 24064
#define MF_HAL_OFF  (24064 + 18944)          // 43008
#define MF_WCH_OFF  (43008 + 18944)          // 61952: 2 bufs x 3 comps x 16KB
#define MF_SMEM     (61952 + 2 * 49152)      // 160256 B (<= 160KB)

// ---------------- f32 fallback LDS layout (round 7, verified) ----------------
#define NCH 16
#define HA_STR 20
#define X_OFF   0
#define HA_OFF  1024
#define W_OFF   (HA_OFF + HSZ * HA_STR)
#define RED_OFF (W_OFF + 3 * 32 * 256)
#define SMEM_FLOATS (RED_OFF + 512)
#define SMEM_BYTES  (SMEM_FLOATS * 4)        // 145408 B

__device__ __forceinline__ void stage16(const void* gp, void* lp) {
    __builtin_amdgcn_global_load_lds(
        (const __attribute__((address_space(1))) void*)gp,
        (__attribute__((address_space(3))) void*)lp, 16, 0, 0);
}

// Tagged-word exchange: value and validity in ONE 8B atomic object. (r6/r7/r10)
__device__ __forceinline__ float wait_tag(const u64* p, unsigned tag) {
    u64 v = __hip_atomic_load(p, __ATOMIC_RELAXED, __HIP_MEMORY_SCOPE_AGENT);
    while ((unsigned)(v >> 32) != tag) {
        __builtin_amdgcn_s_sleep(1);
        v = __hip_atomic_load(p, __ATOMIC_RELAXED, __HIP_MEMORY_SCOPE_AGENT);
    }
    return __uint_as_float((unsigned)v);
}

// bf16 split helpers (RNE)
__device__ __forceinline__ ushort_t f32_to_bf16(float f) {
    unsigned u = __float_as_uint(f);
    unsigned r = u + 0x7FFFu + ((u >> 16) & 1u);
    return (ushort_t)(r >> 16);
}
__device__ __forceinline__ float bf16_to_f32(ushort_t h) {
    return __uint_as_float((unsigned)h << 16);
}

// ---------------------------------------------------------------------------
// Kernel 0a: transpose + 3-way bf16-split Wa2 -> tiled wth/wtm/wtl (r10)
// ---------------------------------------------------------------------------
__global__ __launch_bounds__(256) void wsplit_kernel(
    const float* __restrict__ Wa2,
    ushort_t* __restrict__ wth, ushort_t* __restrict__ wtm,
    ushort_t* __restrict__ wtl)
{
    __shared__ float tile[64][65];
    const int bc = blockIdx.x & 63;
    const int bh = blockIdx.x >> 6;
    const int c0 = bc * 64, h0 = bh * 64;
    const int tid = threadIdx.x;

    const int lr = tid >> 4, lc4 = (tid & 15) * 4;
    #pragma unroll
    for (int p = 0; p < 4; ++p) {
        const int h = p * 16 + lr;
        *(f32x4*)&tile[h][lc4] =
            *(const f32x4*)(Wa2 + (size_t)(h0 + h) * 4096 + c0 + lc4);
    }
    __syncthreads();

    const int col = tid >> 2, hb = (tid & 3) * 16;
    u16x8 H0, H1, M0, M1, L0, L1;
    #pragma unroll
    for (int q = 0; q < 16; ++q) {
        const float v = tile[hb + q][col];
        const ushort_t H = f32_to_bf16(v);
        const float r1 = v - bf16_to_f32(H);
        const ushort_t M = f32_to_bf16(r1);
        const ushort_t L = f32_to_bf16(r1 - bf16_to_f32(M));
        if (q < 8) { H0[q] = H; M0[q] = M; L0[q] = L; }
        else       { H1[q-8] = H; M1[q-8] = M; L1[q-8] = L; }
    }
    const int col_g = c0 + col;
    const int hbase = h0 + hb;
    const int kk    = hbase >> 5;
    const int sl0   = (hbase >> 3) & 3;
    const size_t atom0 = (((size_t)(col_g >> 5) * 16 + kk) * 4 + sl0) * 32
                       + (col_g & 31);
    const size_t atom1 = atom0 + 32;
    *(u16x8*)(wth + atom0 * 8) = H0;  *(u16x8*)(wth + atom1 * 8) = H1;
    *(u16x8*)(wtm + atom0 * 8) = M0;  *(u16x8*)(wtm + atom1 * 8) = M1;
    *(u16x8*)(wtl + atom0 * 8) = L0;  *(u16x8*)(wtl + atom1 * 8) = L1;
}

// ---------------------------------------------------------------------------
// Kernel 0b: 3-way bf16-split Wa1[64][512] -> frag-tiled wa1h/m/l (r12)
// ---------------------------------------------------------------------------
__global__ __launch_bounds__(256) void wsplit_wa1_kernel(
    const float* __restrict__ Wa1,
    ushort_t* __restrict__ wa1h, ushort_t* __restrict__ wa1m,
    ushort_t* __restrict__ wa1l)
{
    const int ht = blockIdx.x;        // 0..15
    const int t  = threadIdx.x;
    const int kk = t >> 7, slot = (t >> 5) & 3, col = t & 31;
    u16x8 H, M, L;
    #pragma unroll
    for (int e = 0; e < 8; ++e) {
        const int j = kk * 32 + slot * 8 + e;
        const float v = Wa1[(size_t)j * HSZ + ht * 32 + col];
        const ushort_t h16 = f32_to_bf16(v);
        const float r1 = v - bf16_to_f32(h16);
        const ushort_t m16 = f32_to_bf16(r1);
        const ushort_t l16 = f32_to_bf16(r1 - bf16_to_f32(m16));
        H[e] = h16; M[e] = m16; L[e] = l16;
    }
    const size_t off = (((size_t)(ht * 2 + kk) * 4 + slot) * 32 + col) * 8;
    *(u16x8*)(wa1h + off) = H;
    *(u16x8*)(wa1m + off) = M;
    *(u16x8*)(wa1l + off) = L;
}

// ---------------------------------------------------------------------------
// Kernel 1: bu[b,t,i] -> d_out[b,t,i]. 16 samples per WG. (unchanged)
// ---------------------------------------------------------------------------
__global__ __launch_bounds__(256) void bu_kernel(
    const float* __restrict__ us,
    const float* __restrict__ Wb1, const float* __restrict__ bb1,
    const float* __restrict__ Wb2, const float* __restrict__ bb2,
    float* __restrict__ out)
{
    __shared__ float u_lds[16][16];
    __shared__ float hb_lds[16][HSZ + 4];

    const int tid = threadIdx.x;
    const long s0 = (long)blockIdx.x * 16;

    u_lds[tid >> 4][tid & 15] = us[s0 * ASZ + tid];
    __syncthreads();

    #pragma unroll
    for (int rep = 0; rep < 2; ++rep) {
        const int h = tid + rep * 256;
        float acc[16];
        const float b1 = bb1[h];
        #pragma unroll
        for (int s = 0; s < 16; ++s) acc[s] = b1;
        #pragma unroll
        for (int a = 0; a < ASZ; ++a) {
            const float w = Wb1[a * HSZ + h];
            #pragma unroll
            for (int s = 0; s < 16; ++s) acc[s] += u_lds[s][a] * w;
        }
        #pragma unroll
        for (int s = 0; s < 16; ++s) hb_lds[s][h] = tanhf(acc[s]);
    }
    __syncthreads();

    const int i  = tid & 63;
    const int sg = tid >> 6;

    float ur[4][ASZ];
    #pragma unroll
    for (int s4 = 0; s4 < 4; ++s4)
        #pragma unroll
        for (int a = 0; a < ASZ; ++a) ur[s4][a] = u_lds[sg * 4 + s4][a];

    float acc[4];
    {
        float wb[ASZ];
        const float4* bp = (const float4*)(bb2 + i * ASZ);
        #pragma unroll
        for (int q = 0; q < 4; ++q) {
            float4 v = bp[q];
            wb[q*4+0] = v.x; wb[q*4+1] = v.y; wb[q*4+2] = v.z; wb[q*4+3] = v.w;
        }
        #pragma unroll
        for (int s4 = 0; s4 < 4; ++s4) {
            float t = 0.f;
            #pragma unroll
            for (int a = 0; a < ASZ; ++a) t += wb[a] * ur[s4][a];
            acc[s4] = t;
        }
    }

    for (int h = 0; h < HSZ; ++h) {
        float w[ASZ];
        const float4* wp = (const float4*)(Wb2 + (size_t)h * (SSZ * ASZ) + i * ASZ);
        #pragma unroll
        for (int q = 0; q < 4; ++q) {
            float4 v = wp[q];
            w[q*4+0] = v.x; w[q*4+1] = v.y; w[q*4+2] = v.z; w[q*4+3] = v.w;
        }
        #pragma unroll
        for (int s4 = 0; s4 < 4; ++s4) {
            float t = 0.f;
            #pragma unroll
            for (int a = 0; a < ASZ; ++a) t += w[a] * ur[s4][a];
            acc[s4] += hb_lds[sg * 4 + s4][h] * t;
        }
    }

    #pragma unroll
    for (int s4 = 0; s4 < 4; ++s4)
        out[(s0 + sg * 4 + s4) * SSZ + i] = acc[s4];
}

// ---------------------------------------------------------------------------
// Kernel 2: MFMA rollout = r13 byte-identical EXCEPT the exchange is
// counter-throttled: producer {tagged stores -> vmcnt(0) -> 1 atomicAdd};
// consumer tid0 polls ONE line (s_sleep backoff) until count==16, THEN all
// lanes do the tagged reads (tags remain the correctness ground truth;
// counter is purely a poll-flood throttle).
// ---------------------------------------------------------------------------
__global__ __launch_bounds__(512, 1) void ssm_mfma(
    const float* __restrict__ x0, const float* __restrict__ ba1,
    const ushort_t* __restrict__ wa1h, const ushort_t* __restrict__ wa1m,
    const ushort_t* __restrict__ wa1l,
    const ushort_t* __restrict__ wth, const ushort_t* __restrict__ wtm,
    const ushort_t* __restrict__ wtl, const float* __restrict__ ba2,
    float* __restrict__ out, u64* __restrict__ xbuf,
    unsigned* __restrict__ cnt)
{
    extern __shared__ char smem[];
    float* x_lds = (float*)(smem + MF_X_OFF);    // [16][XSTR]
    float* red   = (float*)(smem + MF_RED_OFF);
    char*  haH   = smem + MF_HAH_OFF;
    char*  haM   = smem + MF_HAM_OFF;
    char*  haL   = smem + MF_HAL_OFF;
    char*  wch   = smem + MF_WCH_OFF;            // 2 bufs x {H,M,L 16KB}

    const int tid  = threadIdx.x;
    const int lane = tid & 63;
    const int wv   = tid >> 6;
    const int l15  = lane & 15, lg = lane >> 4;
    const int bt = blockIdx.x >> 4, ct = blockIdx.x & 15;
    const long bbase = (long)bt * 16;

    const size_t wtile = (size_t)((ct * 8 + wv) * 16) * 1024 + (size_t)lane * 8;

    const float ba2v0 = ba2[ct * 256 + 32 * wv + l15];
    const float ba2v1 = ba2[ct * 256 + 32 * wv + 16 + l15];
    const int jt  = 32 * (wv & 1) + l15;
    const int s_e = l15, q_e = lg;

    const int abyte  = lg * 288 + l15 * 16;          // + k*1184
    const int b0byte = wv * 2048 + lg * 512 + l15 * 16;
    const int b1byte = b0byte + 256;

    // ba1 per colfrag (h = wv*64 + cf*16 + l15)
    float ba1r[4];
    #pragma unroll
    for (int cf = 0; cf < 4; ++cf) ba1r[cf] = ba1[wv * 64 + cf * 16 + l15];

    // wa1 fragment offsets (compiler decides reg vs reload; tiny L2 set)
    size_t wa1o[4];
    #pragma unroll
    for (int cf = 0; cf < 4; ++cf)
        wa1o[cf] = (((size_t)(wv * 2 + (cf >> 1)) * 2 + 0) * 4 + lg) * 256
                 + ((cf & 1) * 16 + l15) * 8;        // kk=1: +1024

    unsigned* mycnt = cnt + bt * TSZ;

    #define STAGEW(k_) do {                                                   \
        char* db_ = wch + ((k_) & 1) * 49152 + wv * 2048;                     \
        const ushort_t* gH_ = wth + wtile + (size_t)(k_) * 1024;              \
        const ushort_t* gM_ = wtm + wtile + (size_t)(k_) * 1024;              \
        const ushort_t* gL_ = wtl + wtile + (size_t)(k_) * 1024;              \
        stage16(gH_, db_);           stage16(gH_ + 512, db_ + 1024);          \
        stage16(gM_, db_ + 16384);   stage16(gM_ + 512, db_ + 16384 + 1024);  \
        stage16(gL_, db_ + 32768);   stage16(gL_ + 512, db_ + 32768 + 1024);  \
    } while (0)

    for (int t = 0; t < TSZ; ++t) {
        // ---- prestage W chunk 0 (lands under gate / ha phase) ----
        STAGEW(0);

        // ---- bu (wave0; cached load of bytes only bu_kernel wrote) ----
        float bu_v = 0.f;
        if (wv == 0)
            bu_v = out[((bbase + s_e) * TSZ + t) * SSZ + (ct * 4 + q_e)];

        // ---- arrival gate: ONE line polled by tid0, backoff sleep ----
        if (t > 0) {
            if (tid == 0) {
                while (__hip_atomic_load(&mycnt[t - 1], __ATOMIC_RELAXED,
                                         __HIP_MEMORY_SCOPE_AGENT) < 16u)
                    __builtin_amdgcn_s_sleep(2);
            }
            __syncthreads();
        }

        // ---- obtain x_{t-1} (first 4 waves; tagged reads, now ~1 round) ----
        if (tid < 256) {
            const int sx = tid >> 4, jx = (tid & 15) * 4;
            float xv0, xv1, xv2, xv3;
            if (t > 0) {
                const u64* xs = xbuf + (size_t)((t - 1) & 3) * (BSZ * SSZ)
                              + (bbase + sx) * SSZ + jx;
                xv0 = wait_tag(xs + 0, (unsigned)t);
                xv1 = wait_tag(xs + 1, (unsigned)t);
                xv2 = wait_tag(xs + 2, (unsigned)t);
                xv3 = wait_tag(xs + 3, (unsigned)t);
            } else {
                const f32x4 x4 = *(const f32x4*)(x0 + (bbase + sx) * SSZ + jx);
                xv0 = x4.x; xv1 = x4.y; xv2 = x4.z; xv3 = x4.w;
            }
            x_lds[sx * XSTR + jx + 0] = xv0;
            x_lds[sx * XSTR + jx + 1] = xv1;
            x_lds[sx * XSTR + jx + 2] = xv2;
            x_lds[sx * XSTR + jx + 3] = xv3;
        }
        __syncthreads();

        // ---- x fragments: 3-way in-register split (s=l15, j=kk*32+lg*8+e) ----
        bf16x8 xH[2], xM[2], xL[2];
        #pragma unroll
        for (int kk = 0; kk < 2; ++kk) {
            const float* xp = x_lds + l15 * XSTR + kk * 32 + lg * 8;
            const f32x4 a = *(const f32x4*)xp;
            const f32x4 b = *(const f32x4*)(xp + 4);
            #pragma unroll
            for (int e = 0; e < 8; ++e) {
                const float v = (e < 4) ? a[e] : b[e - 4];
                const ushort_t H = f32_to_bf16(v);
                const float r1 = v - bf16_to_f32(H);
                const ushort_t M = f32_to_bf16(r1);
                const ushort_t L = f32_to_bf16(r1 - bf16_to_f32(M));
                xH[kk][e] = (short)H; xM[kk][e] = (short)M; xL[kk][e] = (short)L;
            }
        }

        // ---- ha = tanh(x @ Wa1 + ba1) via MFMA (6-pass), store 3-way tiled ----
        #pragma unroll
        for (int cf = 0; cf < 4; ++cf) {
            const bf16x8 wH0 = *(const bf16x8*)(wa1h + wa1o[cf]);
            const bf16x8 wM0 = *(const bf16x8*)(wa1m + wa1o[cf]);
            const bf16x8 wL0 = *(const bf16x8*)(wa1l + wa1o[cf]);
            const bf16x8 wH1 = *(const bf16x8*)(wa1h + wa1o[cf] + 1024);
            const bf16x8 wM1 = *(const bf16x8*)(wa1m + wa1o[cf] + 1024);
            const bf16x8 wL1 = *(const bf16x8*)(wa1l + wa1o[cf] + 1024);
            f32x4 hacc = {0.f, 0.f, 0.f, 0.f};
            hacc = __builtin_amdgcn_mfma_f32_16x16x32_bf16(xL[0], wH0, hacc, 0, 0, 0);
            hacc = __builtin_amdgcn_mfma_f32_16x16x32_bf16(xM[0], wM0, hacc, 0, 0, 0);
            hacc = __builtin_amdgcn_mfma_f32_16x16x32_bf16(xH[0], wL0, hacc, 0, 0, 0);
            hacc = __builtin_amdgcn_mfma_f32_16x16x32_bf16(xM[0], wH0, hacc, 0, 0, 0);
            hacc = __builtin_amdgcn_mfma_f32_16x16x32_bf16(xH[0], wM0, hacc, 0, 0, 0);
            hacc = __builtin_amdgcn_mfma_f32_16x16x32_bf16(xH[0], wH0, hacc, 0, 0, 0);
            hacc = __builtin_amdgcn_mfma_f32_16x16x32_bf16(xL[1], wH1, hacc, 0, 0, 0);
            hacc = __builtin_amdgcn_mfma_f32_16x16x32_bf16(xM[1], wM1, hacc, 0, 0, 0);
            hacc = __builtin_amdgcn_mfma_f32_16x16x32_bf16(xH[1], wL1, hacc, 0, 0, 0);
            hacc = __builtin_amdgcn_mfma_f32_16x16x32_bf16(xM[1], wH1, hacc, 0, 0, 0);
            hacc = __builtin_amdgcn_mfma_f32_16x16x32_bf16(xH[1], wM1, hacc, 0, 0, 0);
            hacc = __builtin_amdgcn_mfma_f32_16x16x32_bf16(xH[1], wH1, hacc, 0, 0, 0);

            const int kkg = wv * 2 + (cf >> 1);
            const int slt = (cf & 1) * 2 + (l15 >> 3);
            const int hwb = kkg * 1184 + slt * 288 + (l15 & 7) * 2;
            #pragma unroll
            for (int r = 0; r < 4; ++r) {
                const float v = tanhf(hacc[r] + ba1r[cf]);
                const ushort_t H = f32_to_bf16(v);
                const float r1 = v - bf16_to_f32(H);
                const ushort_t M = f32_to_bf16(r1);
                const ushort_t L = f32_to_bf16(r1 - bf16_to_f32(M));
                const int ad = hwb + (lg * 4 + r) * 16;
                *(ushort_t*)(haH + ad) = H;
                *(ushort_t*)(haM + ad) = M;
                *(ushort_t*)(haL + ad) = L;
            }
        }
        __syncthreads();   // ha complete (cross-wave kk ownership)

        // ---- G-GEMM: r10 schedule — stage k+1, counted vmcnt(6) ladder ----
        f32x4 acc0 = {0.f, 0.f, 0.f, 0.f};
        f32x4 acc1 = {0.f, 0.f, 0.f, 0.f};
        #pragma unroll
        for (int k = 0; k < 16; ++k) {
            if (k + 1 < 16) {
                STAGEW(k + 1);
                asm volatile("s_waitcnt vmcnt(6)" ::: "memory"); // chunk k landed
            } else {
                asm volatile("s_waitcnt vmcnt(0)" ::: "memory");
            }
            __builtin_amdgcn_sched_barrier(0);

            const char* wb = wch + (k & 1) * 49152;
            const bf16x8 aH  = *(const bf16x8*)(haH + k * 1184 + abyte);
            const bf16x8 aM  = *(const bf16x8*)(haM + k * 1184 + abyte);
            const bf16x8 aL  = *(const bf16x8*)(haL + k * 1184 + abyte);
            const bf16x8 b0H = *(const bf16x8*)(wb + b0byte);
            const bf16x8 b0M = *(const bf16x8*)(wb + 16384 + b0byte);
            const bf16x8 b0L = *(const bf16x8*)(wb + 32768 + b0byte);
            const bf16x8 b1H = *(const bf16x8*)(wb + b1byte);
            const bf16x8 b1M = *(const bf16x8*)(wb + 16384 + b1byte);
            const bf16x8 b1L = *(const bf16x8*)(wb + 32768 + b1byte);

            // small-first accumulation (identical order to r9/r10)
            acc0 = __builtin_amdgcn_mfma_f32_16x16x32_bf16(aL, b0H, acc0, 0, 0, 0);
            acc0 = __builtin_amdgcn_mfma_f32_16x16x32_bf16(aM, b0M, acc0, 0, 0, 0);
            acc0 = __builtin_amdgcn_mfma_f32_16x16x32_bf16(aH, b0L, acc0, 0, 0, 0);
            acc0 = __builtin_amdgcn_mfma_f32_16x16x32_bf16(aM, b0H, acc0, 0, 0, 0);
            acc0 = __builtin_amdgcn_mfma_f32_16x16x32_bf16(aH, b0M, acc0, 0, 0, 0);
            acc0 = __builtin_amdgcn_mfma_f32_16x16x32_bf16(aH, b0H, acc0, 0, 0, 0);
            acc1 = __builtin_amdgcn_mfma_f32_16x16x32_bf16(aL, b1H, acc1, 0, 0, 0);
            acc1 = __builtin_amdgcn_mfma_f32_16x16x32_bf16(aM, b1M, acc1, 0, 0, 0);
            acc1 = __builtin_amdgcn_mfma_f32_16x16x32_bf16(aH, b1L, acc1, 0, 0, 0);
            acc1 = __builtin_amdgcn_mfma_f32_16x16x32_bf16(aM, b1H, acc1, 0, 0, 0);
            acc1 = __builtin_amdgcn_mfma_f32_16x16x32_bf16(aH, b1M, acc1, 0, 0, 0);
            acc1 = __builtin_amdgcn_mfma_f32_16x16x32_bf16(aH, b1H, acc1, 0, 0, 0);
        }

        // ---- epilogue: +ba2, x-contract, reduce 16 lanes, publish ----
        float part[4];
        #pragma unroll
        for (int r = 0; r < 4; ++r) {
            const int s = lg * 4 + r;                    // C row (m89 layout)
            part[r] = (acc0[r] + ba2v0) * x_lds[s * XSTR + jt]
                    + (acc1[r] + ba2v1) * x_lds[s * XSTR + jt + 16];
            part[r] += __shfl_xor(part[r], 1);
            part[r] += __shfl_xor(part[r], 2);
            part[r] += __shfl_xor(part[r], 4);
            part[r] += __shfl_xor(part[r], 8);
        }
        if (l15 == 0) {
            #pragma unroll
            for (int r = 0; r < 4; ++r)
                red[wv * 16 + lg * 4 + r] = part[r];
        }
        __syncthreads();

        if (wv == 0) {
            const long b = bbase + s_e;
            const int  i = ct * 4 + q_e;
            const float xn = red[(2 * q_e) * 16 + s_e]
                           + red[(2 * q_e + 1) * 16 + s_e] + bu_v;
            out[(b * TSZ + t) * SSZ + i] = xn;           // final (write-once)
            const u64 w = ((u64)(unsigned)(t + 1) << 32)
                        | (u64)__float_as_uint(xn);
            __hip_atomic_store(xbuf + (size_t)(t & 3) * (BSZ * SSZ) + b * SSZ + i,
                               w, __ATOMIC_RELAXED, __HIP_MEMORY_SCOPE_AGENT);
            // arrive: own stores drained, then ONE counter add per WG
            asm volatile("s_waitcnt vmcnt(0)" ::: "memory");
            if (lane == 0)
                __hip_atomic_fetch_add(&mycnt[t], 1u, __ATOMIC_RELAXED,
                                       __HIP_MEMORY_SCOPE_AGENT);
        }
    }
    #undef STAGEW
}

// ---------------------------------------------------------------------------
// Kernel 2 (FALLBACK, round-7 f32 path, used when ws_size < WS_NEEDED)
// ---------------------------------------------------------------------------
__global__ __launch_bounds__(512, 1) void ssm_f32(
    const float* __restrict__ x0,
    const float* __restrict__ Wa1, const float* __restrict__ ba1,
    const float* __restrict__ Wa2, const float* __restrict__ ba2,
    float* __restrict__ out, u64* __restrict__ xbuf)
{
    extern __shared__ float smemf[];
    float* x_lds = smemf + X_OFF;
    float* ha_t  = smemf + HA_OFF;
    float* wchf  = smemf + W_OFF;
    float* redf  = smemf + RED_OFF;

    const int tid  = threadIdx.x;
    const int lane = tid & 63;
    const int wv   = tid >> 6;
    const int bt = blockIdx.x >> 4;
    const int ct = blockIdx.x & 15;
    const long bbase = (long)bt * 16;

    const int c0 = ct * 256 + lane * 4;
    const f32x4 ba2r = *(const f32x4*)(ba2 + c0);
    const int j0 = (lane & 15) * 4;
    const int s_e = lane & 15, il_e = lane >> 4;

    for (int t = 0; t < TSZ; ++t) {
        #pragma unroll
        for (int it = 0; it < 4; ++it)
            stage16(Wa2 + (size_t)(wv * 4 + it) * 4096 + c0,
                    wchf + (0 * 32 + wv * 4 + it) * 256);
        #pragma unroll
        for (int it = 0; it < 4; ++it)
            stage16(Wa2 + (size_t)(32 + wv * 4 + it) * 4096 + c0,
                    wchf + (1 * 32 + wv * 4 + it) * 256);

        float bu_v = 0.f;
        if (wv == 0)
            bu_v = out[((bbase + s_e) * TSZ + t) * SSZ + (ct * 4 + il_e)];

        if (tid < 256) {
            const int sx = tid >> 4, jx = (tid & 15) * 4;
            float xv0, xv1, xv2, xv3;
            if (t > 0) {
                const u64* xs = xbuf + (size_t)((t - 1) & 3) * (BSZ * SSZ)
                              + (bbase + sx) * SSZ + jx;
                xv0 = wait_tag(xs + 0, (unsigned)t);
                xv1 = wait_tag(xs + 1, (unsigned)t);
                xv2 = wait_tag(xs + 2, (unsigned)t);
                xv3 = wait_tag(xs + 3, (unsigned)t);
            } else {
                const f32x4 x4 = *(const f32x4*)(x0 + (bbase + sx) * SSZ + jx);
                xv0 = x4.x; xv1 = x4.y; xv2 = x4.z; xv3 = x4.w;
            }
            x_lds[sx * SSZ + jx + 0] = xv0;
            x_lds[sx * SSZ + jx + 1] = xv1;
            x_lds[sx * SSZ + jx + 2] = xv2;
            x_lds[sx * SSZ + jx + 3] = xv3;
        }
        __syncthreads();

        {
            const int h0 = tid;
            float ar[16];
            const float b0 = ba1[h0];
            #pragma unroll
            for (int s = 0; s < 16; ++s) ar[s] = b0;
            #pragma unroll 4
            for (int jb = 0; jb < 16; ++jb) {
                float w0[4];
                #pragma unroll
                for (int q = 0; q < 4; ++q)
                    w0[q] = Wa1[(jb * 4 + q) * HSZ + h0];
                #pragma unroll
                for (int s = 0; s < 16; ++s) {
                    const f32x4 xr = *(const f32x4*)&x_lds[s * SSZ + jb * 4];
                    ar[s] += xr.x*w0[0] + xr.y*w0[1] + xr.z*w0[2] + xr.w*w0[3];
                }
            }
            #pragma unroll
            for (int s = 0; s < 16; ++s) ar[s] = tanhf(ar[s]);
            #pragma unroll
            for (int q = 0; q < 4; ++q) {
                f32x4 v0;
                v0.x=ar[q*4+0]; v0.y=ar[q*4+1]; v0.z=ar[q*4+2]; v0.w=ar[q*4+3];
                *(f32x4*)&ha_t[h0 * HA_STR + q * 4] = v0;
            }
        }
        __syncthreads();

        f32x4 acc[16];
        {
            const f32x4 zero = {0.f, 0.f, 0.f, 0.f};
            const f32x4 ini = (wv == 0) ? ba2r : zero;
            #pragma unroll
            for (int s = 0; s < 16; ++s) acc[s] = ini;
        }
        for (int k = 0; k < NCH; ++k) {
            if (k + 2 < NCH) {
                #pragma unroll
                for (int it = 0; it < 4; ++it)
                    stage16(Wa2 + (size_t)((k + 2) * 32 + wv * 4 + it) * 4096 + c0,
                            wchf + (((k + 2) % 3) * 32 + wv * 4 + it) * 256);
                asm volatile("s_waitcnt vmcnt(8)" ::: "memory");
            } else if (k + 1 < NCH) {
                asm volatile("s_waitcnt vmcnt(4)" ::: "memory");
            } else {
                asm volatile("s_waitcnt vmcnt(0)" ::: "memory");
            }
            __builtin_amdgcn_sched_barrier(0);

            const float* wb = wchf + (k % 3) * 8192 + (wv * 4) * 256;
            const float* hb = ha_t + (size_t)(k * 32 + wv * 4) * HA_STR;
            #pragma unroll
            for (int rr = 0; rr < 4; ++rr) {
                const f32x4 w4 = *(const f32x4*)(wb + rr * 256 + lane * 4);
                const f32x4 h0 = *(const f32x4*)(hb + rr * HA_STR + 0);
                const f32x4 h1 = *(const f32x4*)(hb + rr * HA_STR + 4);
                const f32x4 h2 = *(const f32x4*)(hb + rr * HA_STR + 8);
                const f32x4 h3 = *(const f32x4*)(hb + rr * HA_STR + 12);
                acc[0]  += h0.x * w4; acc[1]  += h0.y * w4;
                acc[2]  += h0.z * w4; acc[3]  += h0.w * w4;
                acc[4]  += h1.x * w4; acc[5]  += h1.y * w4;
                acc[6]  += h1.z * w4; acc[7]  += h1.w * w4;
                acc[8]  += h2.x * w4; acc[9]  += h2.y * w4;
                acc[10] += h2.z * w4; acc[11] += h2.w * w4;
                acc[12] += h3.x * w4; acc[13] += h3.y * w4;
                acc[14] += h3.z * w4; acc[15] += h3.w * w4;
            }
        }

        float part[16];
        #pragma unroll
        for (int s = 0; s < 16; ++s) {
            const f32x4 xr = *(const f32x4*)&x_lds[s * SSZ + j0];
            part[s] = acc[s].x*xr.x + acc[s].y*xr.y + acc[s].z*xr.z + acc[s].w*xr.w;
        }
        #pragma unroll
        for (int s = 0; s < 16; ++s) {
            part[s] += __shfl_xor(part[s], 1);
            part[s] += __shfl_xor(part[s], 2);
            part[s] += __shfl_xor(part[s], 4);
            part[s] += __shfl_xor(part[s], 8);
        }
        if ((lane & 15) == 0) {
            const int il = lane >> 4;
            #pragma unroll
            for (int s = 0; s < 16; ++s)
                redf[(wv * 4 + il) * 16 + s] = part[s];
        }
        __syncthreads();

        if (wv == 0) {
            const long b = bbase + s_e;
            const int  i = ct * 4 + il_e;
            float r = 0.f;
            #pragma unroll
            for (int w8 = 0; w8 < 8; ++w8)
                r += redf[(w8 * 4 + il_e) * 16 + s_e];
            const float xn = r + bu_v;
            out[(b * TSZ + t) * SSZ + i] = xn;
            const u64 w = ((u64)(unsigned)(t + 1) << 32)
                        | (u64)__float_as_uint(xn);
            __hip_atomic_store(xbuf + (size_t)(t & 3) * (BSZ * SSZ) + b * SSZ + i,
                               w, __ATOMIC_RELAXED, __HIP_MEMORY_SCOPE_AGENT);
        }
    }
}

// ---------------------------------------------------------------------------
extern "C" void kernel_launch(void* const* d_in, const int* in_sizes, int n_in,
                              void* d_out, int out_size, void* d_ws, size_t ws_size,
                              hipStream_t stream) {
    const float* x0  = (const float*)d_in[0];
    const float* us  = (const float*)d_in[1];
    const float* Wa1 = (const float*)d_in[2];
    const float* ba1 = (const float*)d_in[3];
    const float* Wa2 = (const float*)d_in[4];
    const float* ba2 = (const float*)d_in[5];
    const float* Wb1 = (const float*)d_in[6];
    const float* bb1 = (const float*)d_in[7];
    const float* Wb2 = (const float*)d_in[8];
    const float* bb2 = (const float*)d_in[9];
    float* out = (float*)d_out;

    u64* xbuf = (u64*)d_ws;                                   // 512KB
    unsigned* cnt = (unsigned*)((char*)d_ws + XBUF_BYTES);    // 16KB
    // zero tags + counters (captured => runs every replay; replay-safe)
    hipMemsetAsync(d_ws, 0, XBUF_BYTES + CNT_BYTES, stream);

    // Phase 1: bu -> d_out
    hipLaunchKernelGGL(bu_kernel, dim3((BSZ * TSZ) / 16), dim3(256), 0, stream,
                       us, Wb1, bb1, Wb2, bb2, out);

    if (ws_size >= WS_NEEDED) {
        ushort_t* wth  = (ushort_t*)((char*)d_ws + XBUF_BYTES + CNT_BYTES);
        ushort_t* wtm  = wth + WT_ELEMS;
        ushort_t* wtl  = wtm + WT_ELEMS;
        ushort_t* wa1h = wtl + WT_ELEMS;
        ushort_t* wa1m = wa1h + WA1_ELEMS;
        ushort_t* wa1l = wa1m + WA1_ELEMS;
        // Phase 0: pre-split weights
        hipLaunchKernelGGL(wsplit_kernel, dim3(512), dim3(256), 0, stream,
                           Wa2, wth, wtm, wtl);
        hipLaunchKernelGGL(wsplit_wa1_kernel, dim3(16), dim3(256), 0, stream,
                           Wa1, wa1h, wa1m, wa1l);
        (void)hipFuncSetAttribute((const void*)ssm_mfma,
                                  hipFuncAttributeMaxDynamicSharedMemorySize, MF_SMEM);
        void* args[] = {(void*)&x0, (void*)&ba1,
                        (void*)&wa1h, (void*)&wa1m, (void*)&wa1l,
                        (void*)&wth, (void*)&wtm, (void*)&wtl, (void*)&ba2,
                        (void*)&out, (void*)&xbuf, (void*)&cnt};
        hipLaunchCooperativeKernel((const void*)ssm_mfma, dim3(256), dim3(512),
                                   args, MF_SMEM, stream);
    } else {
        (void)hipFuncSetAttribute((const void*)ssm_f32,
                                  hipFuncAttributeMaxDynamicSharedMemorySize, SMEM_BYTES);
        void* args[] = {(void*)&x0, (void*)&Wa1, (void*)&ba1,
                        (void*)&Wa2, (void*)&ba2, (void*)&out, (void*)&xbuf};
        hipLaunchCooperativeKernel((const void*)ssm_f32, dim3(256), dim3(512),
                                   args, SMEM_BYTES, stream);
    }
}

// Round 15
// 7290.846 us; speedup vs baseline: 1.1989x; 1.1989x over previous
//
#include <hip/hip_runtime.h>

#define BSZ 256
#define TSZ 256
#define SSZ 64
#define ASZ 16
#define HSZ 512

typedef float f32x4 __attribute__((ext_vector_type(4)));
typedef short bf16x8 __attribute__((ext_vector_type(8)));
typedef unsigned short u16x8 __attribute__((ext_vector_type(8)));
typedef unsigned long long u64;
typedef unsigned short ushort_t;

// ---------------- workspace layout ----------------
#define XBUF_BYTES ((size_t)4 * BSZ * SSZ * sizeof(u64))              // 512KB
#define CNT_BYTES  ((size_t)16 * TSZ * sizeof(unsigned))              // 16KB
#define WT_ELEMS   ((size_t)4096 * 512)                               // per comp
#define WS_NEEDED  (XBUF_BYTES + CNT_BYTES + 3 * WT_ELEMS * sizeof(ushort_t))

// Tiled W layout (per comp): elem = tile*16384 + kk*1024 + slot*256 + col*8 + e
//   tile = gcol>>5, kk = h>>5, slot = (h>>3)&3, col = gcol&31, e = h&7.
// One (tile,kk) chunk = 1024 elems = 2KB contiguous -> global_load_lds linear.

// ---------------- MFMA ssm LDS layout (bytes) — r10 exact ----------------
#define MF_X_OFF    0                    // [16][64] f32 = 4096
#define MF_RED_OFF  4096                 // [8][16] f32  = 512
#define MF_HAH_OFF  4608                 // [16][520] u16 rows 1040B
#define MF_HAM_OFF  (4608 + 16640)       // 21248
#define MF_HAL_OFF  (21248 + 16640)      // 37888
#define MF_WCH_OFF  (37888 + 16640)      // 54528: 2 bufs x 3 comps x 16KB
#define MF_SMEM     (54528 + 2 * 49152)  // 152832 B

// ---------------- f32 fallback LDS layout (round 7, verified) ----------------
#define NCH 16
#define HA_STR 20
#define X_OFF   0
#define HA_OFF  1024
#define W_OFF   (HA_OFF + HSZ * HA_STR)
#define RED_OFF (W_OFF + 3 * 32 * 256)
#define SMEM_FLOATS (RED_OFF + 512)
#define SMEM_BYTES  (SMEM_FLOATS * 4)    // 145408 B

__device__ __forceinline__ void stage16(const void* gp, void* lp) {
    __builtin_amdgcn_global_load_lds(
        (const __attribute__((address_space(1))) void*)gp,
        (__attribute__((address_space(3))) void*)lp, 16, 0, 0);
}

// Tagged-word exchange: value and validity in ONE 8B atomic object. (r6/r7/r10)
__device__ __forceinline__ float wait_tag(const u64* p, unsigned tag) {
    u64 v = __hip_atomic_load(p, __ATOMIC_RELAXED, __HIP_MEMORY_SCOPE_AGENT);
    while ((unsigned)(v >> 32) != tag) {
        __builtin_amdgcn_s_sleep(1);
        v = __hip_atomic_load(p, __ATOMIC_RELAXED, __HIP_MEMORY_SCOPE_AGENT);
    }
    return __uint_as_float((unsigned)v);
}

// bf16 split helpers (RNE)
__device__ __forceinline__ ushort_t f32_to_bf16(float f) {
    unsigned u = __float_as_uint(f);
    unsigned r = u + 0x7FFFu + ((u >> 16) & 1u);
    return (ushort_t)(r >> 16);
}
__device__ __forceinline__ float bf16_to_f32(ushort_t h) {
    return __uint_as_float((unsigned)h << 16);
}

// ---------------------------------------------------------------------------
// Kernel 0: transpose + 3-way bf16-split Wa2[512][4096] -> tiled wth/wtm/wtl
// ---------------------------------------------------------------------------
__global__ __launch_bounds__(256) void wsplit_kernel(
    const float* __restrict__ Wa2,
    ushort_t* __restrict__ wth, ushort_t* __restrict__ wtm,
    ushort_t* __restrict__ wtl)
{
    __shared__ float tile[64][65];
    const int bc = blockIdx.x & 63;
    const int bh = blockIdx.x >> 6;
    const int c0 = bc * 64, h0 = bh * 64;
    const int tid = threadIdx.x;

    const int lr = tid >> 4, lc4 = (tid & 15) * 4;
    #pragma unroll
    for (int p = 0; p < 4; ++p) {
        const int h = p * 16 + lr;
        *(f32x4*)&tile[h][lc4] =
            *(const f32x4*)(Wa2 + (size_t)(h0 + h) * 4096 + c0 + lc4);
    }
    __syncthreads();

    const int col = tid >> 2, hb = (tid & 3) * 16;
    u16x8 H0, H1, M0, M1, L0, L1;
    #pragma unroll
    for (int q = 0; q < 16; ++q) {
        const float v = tile[hb + q][col];
        const ushort_t H = f32_to_bf16(v);
        const float r1 = v - bf16_to_f32(H);
        const ushort_t M = f32_to_bf16(r1);
        const ushort_t L = f32_to_bf16(r1 - bf16_to_f32(M));
        if (q < 8) { H0[q] = H; M0[q] = M; L0[q] = L; }
        else       { H1[q-8] = H; M1[q-8] = M; L1[q-8] = L; }
    }
    const int col_g = c0 + col;
    const int hbase = h0 + hb;
    const int kk    = hbase >> 5;
    const int sl0   = (hbase >> 3) & 3;
    const size_t atom0 = (((size_t)(col_g >> 5) * 16 + kk) * 4 + sl0) * 32
                       + (col_g & 31);
    const size_t atom1 = atom0 + 32;
    *(u16x8*)(wth + atom0 * 8) = H0;  *(u16x8*)(wth + atom1 * 8) = H1;
    *(u16x8*)(wtm + atom0 * 8) = M0;  *(u16x8*)(wtm + atom1 * 8) = M1;
    *(u16x8*)(wtl + atom0 * 8) = L0;  *(u16x8*)(wtl + atom1 * 8) = L1;
}

// ---------------------------------------------------------------------------
// Kernel 1: bu[b,t,i] -> d_out[b,t,i]. 16 samples per WG. (unchanged)
// ---------------------------------------------------------------------------
__global__ __launch_bounds__(256) void bu_kernel(
    const float* __restrict__ us,
    const float* __restrict__ Wb1, const float* __restrict__ bb1,
    const float* __restrict__ Wb2, const float* __restrict__ bb2,
    float* __restrict__ out)
{
    __shared__ float u_lds[16][16];
    __shared__ float hb_lds[16][HSZ + 4];

    const int tid = threadIdx.x;
    const long s0 = (long)blockIdx.x * 16;

    u_lds[tid >> 4][tid & 15] = us[s0 * ASZ + tid];
    __syncthreads();

    #pragma unroll
    for (int rep = 0; rep < 2; ++rep) {
        const int h = tid + rep * 256;
        float acc[16];
        const float b1 = bb1[h];
        #pragma unroll
        for (int s = 0; s < 16; ++s) acc[s] = b1;
        #pragma unroll
        for (int a = 0; a < ASZ; ++a) {
            const float w = Wb1[a * HSZ + h];
            #pragma unroll
            for (int s = 0; s < 16; ++s) acc[s] += u_lds[s][a] * w;
        }
        #pragma unroll
        for (int s = 0; s < 16; ++s) hb_lds[s][h] = tanhf(acc[s]);
    }
    __syncthreads();

    const int i  = tid & 63;
    const int sg = tid >> 6;

    float ur[4][ASZ];
    #pragma unroll
    for (int s4 = 0; s4 < 4; ++s4)
        #pragma unroll
        for (int a = 0; a < ASZ; ++a) ur[s4][a] = u_lds[sg * 4 + s4][a];

    float acc[4];
    {
        float wb[ASZ];
        const float4* bp = (const float4*)(bb2 + i * ASZ);
        #pragma unroll
        for (int q = 0; q < 4; ++q) {
            float4 v = bp[q];
            wb[q*4+0] = v.x; wb[q*4+1] = v.y; wb[q*4+2] = v.z; wb[q*4+3] = v.w;
        }
        #pragma unroll
        for (int s4 = 0; s4 < 4; ++s4) {
            float t = 0.f;
            #pragma unroll
            for (int a = 0; a < ASZ; ++a) t += wb[a] * ur[s4][a];
            acc[s4] = t;
        }
    }

    for (int h = 0; h < HSZ; ++h) {
        float w[ASZ];
        const float4* wp = (const float4*)(Wb2 + (size_t)h * (SSZ * ASZ) + i * ASZ);
        #pragma unroll
        for (int q = 0; q < 4; ++q) {
            float4 v = wp[q];
            w[q*4+0] = v.x; w[q*4+1] = v.y; w[q*4+2] = v.z; w[q*4+3] = v.w;
        }
        #pragma unroll
        for (int s4 = 0; s4 < 4; ++s4) {
            float t = 0.f;
            #pragma unroll
            for (int a = 0; a < ASZ; ++a) t += w[a] * ur[s4][a];
            acc[s4] += hb_lds[sg * 4 + s4][h] * t;
        }
    }

    #pragma unroll
    for (int s4 = 0; s4 < 4; ++s4)
        out[(s0 + sg * 4 + s4) * SSZ + i] = acc[s4];
}

// ---------------------------------------------------------------------------
// Kernel 2: r10-exact MFMA rollout (VALU ha + 3-way tiled-W global_load_lds
// staging, 2 bufs, vmcnt(6) ladder, serial wait_tag) + r14 arrival gate:
// tid0 polls ONE counter line, then tagged reads (~1 round); producer does
// tagged stores -> vmcnt(0) -> one atomicAdd. Tags = correctness truth.
// NO per-step per-lane global fragment loads anywhere (the r11-r14 trap).
// ---------------------------------------------------------------------------
__global__ __launch_bounds__(512, 1) void ssm_mfma(
    const float* __restrict__ x0,
    const float* __restrict__ Wa1, const float* __restrict__ ba1,
    const ushort_t* __restrict__ wth, const ushort_t* __restrict__ wtm,
    const ushort_t* __restrict__ wtl, const float* __restrict__ ba2,
    float* __restrict__ out, u64* __restrict__ xbuf,
    unsigned* __restrict__ cnt)
{
    extern __shared__ char smem[];
    float* x_lds = (float*)(smem + MF_X_OFF);
    float* red   = (float*)(smem + MF_RED_OFF);
    char*  haH   = smem + MF_HAH_OFF;     // [16][520] u16, row 1040B
    char*  haM   = smem + MF_HAM_OFF;
    char*  haL   = smem + MF_HAL_OFF;
    char*  wch   = smem + MF_WCH_OFF;     // 2 bufs x {H,M,L 16KB each}

    const int tid  = threadIdx.x;
    const int lane = tid & 63;
    const int wv   = tid >> 6;
    const int l15  = lane & 15, lg = lane >> 4;
    const int bt = blockIdx.x >> 4, ct = blockIdx.x & 15;
    const long bbase = (long)bt * 16;

    const size_t wtile = (size_t)((ct * 8 + wv) * 16) * 1024 + (size_t)lane * 8;

    const float ba2v0 = ba2[ct * 256 + 32 * wv + l15];
    const float ba2v1 = ba2[ct * 256 + 32 * wv + 16 + l15];
    const int jt  = 32 * (wv & 1) + l15;
    const int s_e = l15, q_e = lg;

    const int abyte  = l15 * 1040 + lg * 16;
    const int b0byte = wv * 2048 + lg * 512 + l15 * 16;
    const int b1byte = b0byte + 256;

    unsigned* mycnt = cnt + bt * TSZ;

    for (int t = 0; t < TSZ; ++t) {
        // ---- prestage chunk 0 -> buf 0 (lands under gate/ha) ----
        {
            char* db = wch + wv * 2048;
            const ushort_t* gH = wth + wtile;
            const ushort_t* gM = wtm + wtile;
            const ushort_t* gL = wtl + wtile;
            stage16(gH, db);           stage16(gH + 512, db + 1024);
            stage16(gM, db + 16384);   stage16(gM + 512, db + 16384 + 1024);
            stage16(gL, db + 32768);   stage16(gL + 512, db + 32768 + 1024);
        }

        // ---- bu (wave0; cached load of bytes only bu_kernel wrote) ----
        float bu_v = 0.f;
        if (wv == 0)
            bu_v = out[((bbase + s_e) * TSZ + t) * SSZ + (ct * 4 + q_e)];

        // ---- arrival gate: ONE line polled by tid0, backoff sleep ----
        if (t > 0) {
            if (tid == 0) {
                while (__hip_atomic_load(&mycnt[t - 1], __ATOMIC_RELAXED,
                                         __HIP_MEMORY_SCOPE_AGENT) < 16u)
                    __builtin_amdgcn_s_sleep(2);
            }
            __syncthreads();
        }

        // ---- obtain x_{t-1} (first 4 waves; tagged reads, ~1 round) ----
        if (tid < 256) {
            const int sx = tid >> 4, jx = (tid & 15) * 4;
            float xv0, xv1, xv2, xv3;
            if (t > 0) {
                const u64* xs = xbuf + (size_t)((t - 1) & 3) * (BSZ * SSZ)
                              + (bbase + sx) * SSZ + jx;
                xv0 = wait_tag(xs + 0, (unsigned)t);
                xv1 = wait_tag(xs + 1, (unsigned)t);
                xv2 = wait_tag(xs + 2, (unsigned)t);
                xv3 = wait_tag(xs + 3, (unsigned)t);
            } else {
                const f32x4 x4 = *(const f32x4*)(x0 + (bbase + sx) * SSZ + jx);
                xv0 = x4.x; xv1 = x4.y; xv2 = x4.z; xv3 = x4.w;
            }
            x_lds[sx * SSZ + jx + 0] = xv0;
            x_lds[sx * SSZ + jx + 1] = xv1;
            x_lds[sx * SSZ + jx + 2] = xv2;
            x_lds[sx * SSZ + jx + 3] = xv3;
        }
        __syncthreads();

        // ---- ha = tanh(x @ Wa1 + ba1) -> 3-way bf16 split in LDS [s][h] ----
        {
            const int h0 = tid;
            float ar[16];
            const float b0 = ba1[h0];
            #pragma unroll
            for (int s = 0; s < 16; ++s) ar[s] = b0;
            #pragma unroll 4
            for (int jb = 0; jb < 16; ++jb) {
                float w0[4];
                #pragma unroll
                for (int q = 0; q < 4; ++q)
                    w0[q] = Wa1[(jb * 4 + q) * HSZ + h0];
                #pragma unroll
                for (int s = 0; s < 16; ++s) {
                    const f32x4 xr = *(const f32x4*)&x_lds[s * SSZ + jb * 4];
                    ar[s] += xr.x*w0[0] + xr.y*w0[1] + xr.z*w0[2] + xr.w*w0[3];
                }
            }
            #pragma unroll
            for (int s = 0; s < 16; ++s) {
                const float v = tanhf(ar[s]);
                const ushort_t H = f32_to_bf16(v);
                const float r1 = v - bf16_to_f32(H);
                const ushort_t M = f32_to_bf16(r1);
                const ushort_t L = f32_to_bf16(r1 - bf16_to_f32(M));
                ((ushort_t*)(haH + s * 1040))[h0] = H;
                ((ushort_t*)(haM + s * 1040))[h0] = M;
                ((ushort_t*)(haL + s * 1040))[h0] = L;
            }
        }
        __syncthreads();   // ha complete (cross-wave h ownership)

        // ---- MFMA G-GEMM: 16 K-chunks, 6-pass 3x3 split, vmcnt(6) ladder ----
        f32x4 acc0 = {0.f, 0.f, 0.f, 0.f};
        f32x4 acc1 = {0.f, 0.f, 0.f, 0.f};
        #pragma unroll
        for (int k = 0; k < 16; ++k) {
            if (k + 1 < 16) {
                char* db = wch + ((k + 1) & 1) * 49152 + wv * 2048;
                const ushort_t* gH = wth + wtile + (size_t)(k + 1) * 1024;
                const ushort_t* gM = wtm + wtile + (size_t)(k + 1) * 1024;
                const ushort_t* gL = wtl + wtile + (size_t)(k + 1) * 1024;
                stage16(gH, db);           stage16(gH + 512, db + 1024);
                stage16(gM, db + 16384);   stage16(gM + 512, db + 16384 + 1024);
                stage16(gL, db + 32768);   stage16(gL + 512, db + 32768 + 1024);
                asm volatile("s_waitcnt vmcnt(6)" ::: "memory"); // chunk k landed
            } else {
                asm volatile("s_waitcnt vmcnt(0)" ::: "memory");
            }
            __builtin_amdgcn_sched_barrier(0);

            const char* wb = wch + (k & 1) * 49152;
            const bf16x8 aH  = *(const bf16x8*)(haH + k * 64 + abyte);
            const bf16x8 aM  = *(const bf16x8*)(haM + k * 64 + abyte);
            const bf16x8 aL  = *(const bf16x8*)(haL + k * 64 + abyte);
            const bf16x8 b0H = *(const bf16x8*)(wb + b0byte);
            const bf16x8 b0M = *(const bf16x8*)(wb + 16384 + b0byte);
            const bf16x8 b0L = *(const bf16x8*)(wb + 32768 + b0byte);
            const bf16x8 b1H = *(const bf16x8*)(wb + b1byte);
            const bf16x8 b1M = *(const bf16x8*)(wb + 16384 + b1byte);
            const bf16x8 b1L = *(const bf16x8*)(wb + 32768 + b1byte);

            // small-first accumulation (identical order to r9/r10)
            acc0 = __builtin_amdgcn_mfma_f32_16x16x32_bf16(aL, b0H, acc0, 0, 0, 0);
            acc0 = __builtin_amdgcn_mfma_f32_16x16x32_bf16(aM, b0M, acc0, 0, 0, 0);
            acc0 = __builtin_amdgcn_mfma_f32_16x16x32_bf16(aH, b0L, acc0, 0, 0, 0);
            acc0 = __builtin_amdgcn_mfma_f32_16x16x32_bf16(aM, b0H, acc0, 0, 0, 0);
            acc0 = __builtin_amdgcn_mfma_f32_16x16x32_bf16(aH, b0M, acc0, 0, 0, 0);
            acc0 = __builtin_amdgcn_mfma_f32_16x16x32_bf16(aH, b0H, acc0, 0, 0, 0);
            acc1 = __builtin_amdgcn_mfma_f32_16x16x32_bf16(aL, b1H, acc1, 0, 0, 0);
            acc1 = __builtin_amdgcn_mfma_f32_16x16x32_bf16(aM, b1M, acc1, 0, 0, 0);
            acc1 = __builtin_amdgcn_mfma_f32_16x16x32_bf16(aH, b1L, acc1, 0, 0, 0);
            acc1 = __builtin_amdgcn_mfma_f32_16x16x32_bf16(aM, b1H, acc1, 0, 0, 0);
            acc1 = __builtin_amdgcn_mfma_f32_16x16x32_bf16(aH, b1M, acc1, 0, 0, 0);
            acc1 = __builtin_amdgcn_mfma_f32_16x16x32_bf16(aH, b1H, acc1, 0, 0, 0);
        }

        // ---- epilogue: +ba2, x-contract, reduce 16 lanes, publish ----
        float part[4];
        #pragma unroll
        for (int r = 0; r < 4; ++r) {
            const int s = lg * 4 + r;                    // C row (m89 layout)
            part[r] = (acc0[r] + ba2v0) * x_lds[s * SSZ + jt]
                    + (acc1[r] + ba2v1) * x_lds[s * SSZ + jt + 16];
            part[r] += __shfl_xor(part[r], 1);
            part[r] += __shfl_xor(part[r], 2);
            part[r] += __shfl_xor(part[r], 4);
            part[r] += __shfl_xor(part[r], 8);
        }
        if (l15 == 0) {
            #pragma unroll
            for (int r = 0; r < 4; ++r)
                red[wv * 16 + lg * 4 + r] = part[r];
        }
        __syncthreads();

        if (wv == 0) {
            const long b = bbase + s_e;
            const int  i = ct * 4 + q_e;
            const float xn = red[(2 * q_e) * 16 + s_e]
                           + red[(2 * q_e + 1) * 16 + s_e] + bu_v;
            out[(b * TSZ + t) * SSZ + i] = xn;           // final (write-once)
            const u64 w = ((u64)(unsigned)(t + 1) << 32)
                        | (u64)__float_as_uint(xn);
            __hip_atomic_store(xbuf + (size_t)(t & 3) * (BSZ * SSZ) + b * SSZ + i,
                               w, __ATOMIC_RELAXED, __HIP_MEMORY_SCOPE_AGENT);
            // arrive: own stores drained, then ONE counter add per WG
            asm volatile("s_waitcnt vmcnt(0)" ::: "memory");
            if (lane == 0)
                __hip_atomic_fetch_add(&mycnt[t], 1u, __ATOMIC_RELAXED,
                                       __HIP_MEMORY_SCOPE_AGENT);
        }
    }
}

// ---------------------------------------------------------------------------
// Kernel 2 (FALLBACK, round-7 f32 path, used when ws_size < WS_NEEDED)
// ---------------------------------------------------------------------------
__global__ __launch_bounds__(512, 1) void ssm_f32(
    const float* __restrict__ x0,
    const float* __restrict__ Wa1, const float* __restrict__ ba1,
    const float* __restrict__ Wa2, const float* __restrict__ ba2,
    float* __restrict__ out, u64* __restrict__ xbuf)
{
    extern __shared__ float smemf[];
    float* x_lds = smemf + X_OFF;
    float* ha_t  = smemf + HA_OFF;
    float* wchf  = smemf + W_OFF;
    float* redf  = smemf + RED_OFF;

    const int tid  = threadIdx.x;
    const int lane = tid & 63;
    const int wv   = tid >> 6;
    const int bt = blockIdx.x >> 4;
    const int ct = blockIdx.x & 15;
    const long bbase = (long)bt * 16;

    const int c0 = ct * 256 + lane * 4;
    const f32x4 ba2r = *(const f32x4*)(ba2 + c0);
    const int j0 = (lane & 15) * 4;
    const int s_e = lane & 15, il_e = lane >> 4;

    for (int t = 0; t < TSZ; ++t) {
        #pragma unroll
        for (int it = 0; it < 4; ++it)
            stage16(Wa2 + (size_t)(wv * 4 + it) * 4096 + c0,
                    wchf + (0 * 32 + wv * 4 + it) * 256);
        #pragma unroll
        for (int it = 0; it < 4; ++it)
            stage16(Wa2 + (size_t)(32 + wv * 4 + it) * 4096 + c0,
                    wchf + (1 * 32 + wv * 4 + it) * 256);

        float bu_v = 0.f;
        if (wv == 0)
            bu_v = out[((bbase + s_e) * TSZ + t) * SSZ + (ct * 4 + il_e)];

        if (tid < 256) {
            const int sx = tid >> 4, jx = (tid & 15) * 4;
            float xv0, xv1, xv2, xv3;
            if (t > 0) {
                const u64* xs = xbuf + (size_t)((t - 1) & 3) * (BSZ * SSZ)
                              + (bbase + sx) * SSZ + jx;
                xv0 = wait_tag(xs + 0, (unsigned)t);
                xv1 = wait_tag(xs + 1, (unsigned)t);
                xv2 = wait_tag(xs + 2, (unsigned)t);
                xv3 = wait_tag(xs + 3, (unsigned)t);
            } else {
                const f32x4 x4 = *(const f32x4*)(x0 + (bbase + sx) * SSZ + jx);
                xv0 = x4.x; xv1 = x4.y; xv2 = x4.z; xv3 = x4.w;
            }
            x_lds[sx * SSZ + jx + 0] = xv0;
            x_lds[sx * SSZ + jx + 1] = xv1;
            x_lds[sx * SSZ + jx + 2] = xv2;
            x_lds[sx * SSZ + jx + 3] = xv3;
        }
        __syncthreads();

        {
            const int h0 = tid;
            float ar[16];
            const float b0 = ba1[h0];
            #pragma unroll
            for (int s = 0; s < 16; ++s) ar[s] = b0;
            #pragma unroll 4
            for (int jb = 0; jb < 16; ++jb) {
                float w0[4];
                #pragma unroll
                for (int q = 0; q < 4; ++q)
                    w0[q] = Wa1[(jb * 4 + q) * HSZ + h0];
                #pragma unroll
                for (int s = 0; s < 16; ++s) {
                    const f32x4 xr = *(const f32x4*)&x_lds[s * SSZ + jb * 4];
                    ar[s] += xr.x*w0[0] + xr.y*w0[1] + xr.z*w0[2] + xr.w*w0[3];
                }
            }
            #pragma unroll
            for (int s = 0; s < 16; ++s) ar[s] = tanhf(ar[s]);
            #pragma unroll
            for (int q = 0; q < 4; ++q) {
                f32x4 v0;
                v0.x=ar[q*4+0]; v0.y=ar[q*4+1]; v0.z=ar[q*4+2]; v0.w=ar[q*4+3];
                *(f32x4*)&ha_t[h0 * HA_STR + q * 4] = v0;
            }
        }
        __syncthreads();

        f32x4 acc[16];
        {
            const f32x4 zero = {0.f, 0.f, 0.f, 0.f};
            const f32x4 ini = (wv == 0) ? ba2r : zero;
            #pragma unroll
            for (int s = 0; s < 16; ++s) acc[s] = ini;
        }
        for (int k = 0; k < NCH; ++k) {
            if (k + 2 < NCH) {
                #pragma unroll
                for (int it = 0; it < 4; ++it)
                    stage16(Wa2 + (size_t)((k + 2) * 32 + wv * 4 + it) * 4096 + c0,
                            wchf + (((k + 2) % 3) * 32 + wv * 4 + it) * 256);
                asm volatile("s_waitcnt vmcnt(8)" ::: "memory");
            } else if (k + 1 < NCH) {
                asm volatile("s_waitcnt vmcnt(4)" ::: "memory");
            } else {
                asm volatile("s_waitcnt vmcnt(0)" ::: "memory");
            }
            __builtin_amdgcn_sched_barrier(0);

            const float* wb = wchf + (k % 3) * 8192 + (wv * 4) * 256;
            const float* hb = ha_t + (size_t)(k * 32 + wv * 4) * HA_STR;
            #pragma unroll
            for (int rr = 0; rr < 4; ++rr) {
                const f32x4 w4 = *(const f32x4*)(wb + rr * 256 + lane * 4);
                const f32x4 h0 = *(const f32x4*)(hb + rr * HA_STR + 0);
                const f32x4 h1 = *(const f32x4*)(hb + rr * HA_STR + 4);
                const f32x4 h2 = *(const f32x4*)(hb + rr * HA_STR + 8);
                const f32x4 h3 = *(const f32x4*)(hb + rr * HA_STR + 12);
                acc[0]  += h0.x * w4; acc[1]  += h0.y * w4;
                acc[2]  += h0.z * w4; acc[3]  += h0.w * w4;
                acc[4]  += h1.x * w4; acc[5]  += h1.y * w4;
                acc[6]  += h1.z * w4; acc[7]  += h1.w * w4;
                acc[8]  += h2.x * w4; acc[9]  += h2.y * w4;
                acc[10] += h2.z * w4; acc[11] += h2.w * w4;
                acc[12] += h3.x * w4; acc[13] += h3.y * w4;
                acc[14] += h3.z * w4; acc[15] += h3.w * w4;
            }
        }

        float part[16];
        #pragma unroll
        for (int s = 0; s < 16; ++s) {
            const f32x4 xr = *(const f32x4*)&x_lds[s * SSZ + j0];
            part[s] = acc[s].x*xr.x + acc[s].y*xr.y + acc[s].z*xr.z + acc[s].w*xr.w;
        }
        #pragma unroll
        for (int s = 0; s < 16; ++s) {
            part[s] += __shfl_xor(part[s], 1);
            part[s] += __shfl_xor(part[s], 2);
            part[s] += __shfl_xor(part[s], 4);
            part[s] += __shfl_xor(part[s], 8);
        }
        if ((lane & 15) == 0) {
            const int il = lane >> 4;
            #pragma unroll
            for (int s = 0; s < 16; ++s)
                redf[(wv * 4 + il) * 16 + s] = part[s];
        }
        __syncthreads();

        if (wv == 0) {
            const long b = bbase + s_e;
            const int  i = ct * 4 + il_e;
            float r = 0.f;
            #pragma unroll
            for (int w8 = 0; w8 < 8; ++w8)
                r += redf[(w8 * 4 + il_e) * 16 + s_e];
            const float xn = r + bu_v;
            out[(b * TSZ + t) * SSZ + i] = xn;
            const u64 w = ((u64)(unsigned)(t + 1) << 32)
                        | (u64)__float_as_uint(xn);
            __hip_atomic_store(xbuf + (size_t)(t & 3) * (BSZ * SSZ) + b * SSZ + i,
                               w, __ATOMIC_RELAXED, __HIP_MEMORY_SCOPE_AGENT);
        }
    }
}

// ---------------------------------------------------------------------------
extern "C" void kernel_launch(void* const* d_in, const int* in_sizes, int n_in,
                              void* d_out, int out_size, void* d_ws, size_t ws_size,
                              hipStream_t stream) {
    const float* x0  = (const float*)d_in[0];
    const float* us  = (const float*)d_in[1];
    const float* Wa1 = (const float*)d_in[2];
    const float* ba1 = (const float*)d_in[3];
    const float* Wa2 = (const float*)d_in[4];
    const float* ba2 = (const float*)d_in[5];
    const float* Wb1 = (const float*)d_in[6];
    const float* bb1 = (const float*)d_in[7];
    const float* Wb2 = (const float*)d_in[8];
    const float* bb2 = (const float*)d_in[9];
    float* out = (float*)d_out;

    u64* xbuf = (u64*)d_ws;                                   // 512KB
    unsigned* cnt = (unsigned*)((char*)d_ws + XBUF_BYTES);    // 16KB
    // zero tags + counters (captured => runs every replay; replay-safe)
    hipMemsetAsync(d_ws, 0, XBUF_BYTES + CNT_BYTES, stream);

    // Phase 1: bu -> d_out
    hipLaunchKernelGGL(bu_kernel, dim3((BSZ * TSZ) / 16), dim3(256), 0, stream,
                       us, Wb1, bb1, Wb2, bb2, out);

    if (ws_size >= WS_NEEDED) {
        ushort_t* wth = (ushort_t*)((char*)d_ws + XBUF_BYTES + CNT_BYTES);
        ushort_t* wtm = wth + WT_ELEMS;
        ushort_t* wtl = wtm + WT_ELEMS;
        // Phase 0: transpose + 3-way split Wa2 into tiled layout
        hipLaunchKernelGGL(wsplit_kernel, dim3(512), dim3(256), 0, stream,
                           Wa2, wth, wtm, wtl);
        (void)hipFuncSetAttribute((const void*)ssm_mfma,
                                  hipFuncAttributeMaxDynamicSharedMemorySize, MF_SMEM);
        void* args[] = {(void*)&x0, (void*)&Wa1, (void*)&ba1,
                        (void*)&wth, (void*)&wtm, (void*)&wtl, (void*)&ba2,
                        (void*)&out, (void*)&xbuf, (void*)&cnt};
        hipLaunchCooperativeKernel((const void*)ssm_mfma, dim3(256), dim3(512),
                                   args, MF_SMEM, stream);
    } else {
        (void)hipFuncSetAttribute((const void*)ssm_f32,
                                  hipFuncAttributeMaxDynamicSharedMemorySize, SMEM_BYTES);
        void* args[] = {(void*)&x0, (void*)&Wa1, (void*)&ba1,
                        (void*)&Wa2, (void*)&ba2, (void*)&out, (void*)&xbuf};
        hipLaunchCooperativeKernel((const void*)ssm_f32, dim3(256), dim3(512),
                                   args, SMEM_BYTES, stream);
    }
}

// Round 18
// 7284.285 us; speedup vs baseline: 1.2000x; 1.0009x over previous
//
#include <hip/hip_runtime.h>

#define BSZ 256
#define TSZ 256
#define SSZ 64
#define ASZ 16
#define HSZ 512

typedef float f32x4 __attribute__((ext_vector_type(4)));
typedef short bf16x8 __attribute__((ext_vector_type(8)));
typedef unsigned short u16x8 __attribute__((ext_vector_type(8)));
typedef unsigned long long u64;
typedef unsigned short ushort_t;

// ---------------- workspace layout ----------------
#define XBUF_BYTES ((size_t)4 * BSZ * SSZ * sizeof(u64))              // 512KB
#define CNT_BYTES  ((size_t)16 * TSZ * sizeof(unsigned))              // 16KB
#define WT_ELEMS   ((size_t)4096 * 512)                               // per comp
#define WS_NEEDED  (XBUF_BYTES + CNT_BYTES + 3 * WT_ELEMS * sizeof(ushort_t))

// Tiled W layout (per comp): elem = tile*16384 + kk*1024 + slot*256 + col*8 + e
//   tile = gcol>>5, kk = h>>5, slot = (h>>3)&3, col = gcol&31, e = h&7.
// One (tile,kk) chunk = 1024 elems = 2KB contiguous -> global_load_lds linear.

// ---------------- MFMA ssm LDS layout (bytes) — r10 exact ----------------
#define MF_X_OFF    0                    // [16][64] f32 = 4096
#define MF_RED_OFF  4096                 // [8][16] f32  = 512
#define MF_HAH_OFF  4608                 // [16][520] u16 rows 1040B
#define MF_HAM_OFF  (4608 + 16640)       // 21248
#define MF_HAL_OFF  (21248 + 16640)      // 37888
#define MF_WCH_OFF  (37888 + 16640)      // 54528: 2 bufs x 3 comps x 16KB
#define MF_SMEM     (54528 + 2 * 49152)  // 152832 B

// ---------------- f32 fallback LDS layout (round 7, verified) ----------------
#define NCH 16
#define HA_STR 20
#define X_OFF   0
#define HA_OFF  1024
#define W_OFF   (HA_OFF + HSZ * HA_STR)
#define RED_OFF (W_OFF + 3 * 32 * 256)
#define SMEM_FLOATS (RED_OFF + 512)
#define SMEM_BYTES  (SMEM_FLOATS * 4)    // 145408 B

__device__ __forceinline__ void stage16(const void* gp, void* lp) {
    __builtin_amdgcn_global_load_lds(
        (const __attribute__((address_space(1))) void*)gp,
        (__attribute__((address_space(3))) void*)lp, 16, 0, 0);
}

// Tagged-word exchange: value and validity in ONE 8B atomic object. (r6/r7/r10)
__device__ __forceinline__ float wait_tag(const u64* p, unsigned tag) {
    u64 v = __hip_atomic_load(p, __ATOMIC_RELAXED, __HIP_MEMORY_SCOPE_AGENT);
    while ((unsigned)(v >> 32) != tag) {
        __builtin_amdgcn_s_sleep(1);
        v = __hip_atomic_load(p, __ATOMIC_RELAXED, __HIP_MEMORY_SCOPE_AGENT);
    }
    return __uint_as_float((unsigned)v);
}

// bf16 split helpers (RNE)
__device__ __forceinline__ ushort_t f32_to_bf16(float f) {
    unsigned u = __float_as_uint(f);
    unsigned r = u + 0x7FFFu + ((u >> 16) & 1u);
    return (ushort_t)(r >> 16);
}
__device__ __forceinline__ float bf16_to_f32(ushort_t h) {
    return __uint_as_float((unsigned)h << 16);
}

// ---------------------------------------------------------------------------
// Kernel 0: transpose + 3-way bf16-split Wa2[512][4096] -> tiled wth/wtm/wtl
// ---------------------------------------------------------------------------
__global__ __launch_bounds__(256) void wsplit_kernel(
    const float* __restrict__ Wa2,
    ushort_t* __restrict__ wth, ushort_t* __restrict__ wtm,
    ushort_t* __restrict__ wtl)
{
    __shared__ float tile[64][65];
    const int bc = blockIdx.x & 63;
    const int bh = blockIdx.x >> 6;
    const int c0 = bc * 64, h0 = bh * 64;
    const int tid = threadIdx.x;

    const int lr = tid >> 4, lc4 = (tid & 15) * 4;
    #pragma unroll
    for (int p = 0; p < 4; ++p) {
        const int h = p * 16 + lr;
        *(f32x4*)&tile[h][lc4] =
            *(const f32x4*)(Wa2 + (size_t)(h0 + h) * 4096 + c0 + lc4);
    }
    __syncthreads();

    const int col = tid >> 2, hb = (tid & 3) * 16;
    u16x8 H0, H1, M0, M1, L0, L1;
    #pragma unroll
    for (int q = 0; q < 16; ++q) {
        const float v = tile[hb + q][col];
        const ushort_t H = f32_to_bf16(v);
        const float r1 = v - bf16_to_f32(H);
        const ushort_t M = f32_to_bf16(r1);
        const ushort_t L = f32_to_bf16(r1 - bf16_to_f32(M));
        if (q < 8) { H0[q] = H; M0[q] = M; L0[q] = L; }
        else       { H1[q-8] = H; M1[q-8] = M; L1[q-8] = L; }
    }
    const int col_g = c0 + col;
    const int hbase = h0 + hb;
    const int kk    = hbase >> 5;
    const int sl0   = (hbase >> 3) & 3;
    const size_t atom0 = (((size_t)(col_g >> 5) * 16 + kk) * 4 + sl0) * 32
                       + (col_g & 31);
    const size_t atom1 = atom0 + 32;
    *(u16x8*)(wth + atom0 * 8) = H0;  *(u16x8*)(wth + atom1 * 8) = H1;
    *(u16x8*)(wtm + atom0 * 8) = M0;  *(u16x8*)(wtm + atom1 * 8) = M1;
    *(u16x8*)(wtl + atom0 * 8) = L0;  *(u16x8*)(wtl + atom1 * 8) = L1;
}

// ---------------------------------------------------------------------------
// Kernel 1: bu[b,t,i] -> d_out[b,t,i]. 16 samples per WG. (unchanged)
// ---------------------------------------------------------------------------
__global__ __launch_bounds__(256) void bu_kernel(
    const float* __restrict__ us,
    const float* __restrict__ Wb1, const float* __restrict__ bb1,
    const float* __restrict__ Wb2, const float* __restrict__ bb2,
    float* __restrict__ out)
{
    __shared__ float u_lds[16][16];
    __shared__ float hb_lds[16][HSZ + 4];

    const int tid = threadIdx.x;
    const long s0 = (long)blockIdx.x * 16;

    u_lds[tid >> 4][tid & 15] = us[s0 * ASZ + tid];
    __syncthreads();

    #pragma unroll
    for (int rep = 0; rep < 2; ++rep) {
        const int h = tid + rep * 256;
        float acc[16];
        const float b1 = bb1[h];
        #pragma unroll
        for (int s = 0; s < 16; ++s) acc[s] = b1;
        #pragma unroll
        for (int a = 0; a < ASZ; ++a) {
            const float w = Wb1[a * HSZ + h];
            #pragma unroll
            for (int s = 0; s < 16; ++s) acc[s] += u_lds[s][a] * w;
        }
        #pragma unroll
        for (int s = 0; s < 16; ++s) hb_lds[s][h] = tanhf(acc[s]);
    }
    __syncthreads();

    const int i  = tid & 63;
    const int sg = tid >> 6;

    float ur[4][ASZ];
    #pragma unroll
    for (int s4 = 0; s4 < 4; ++s4)
        #pragma unroll
        for (int a = 0; a < ASZ; ++a) ur[s4][a] = u_lds[sg * 4 + s4][a];

    float acc[4];
    {
        float wb[ASZ];
        const float4* bp = (const float4*)(bb2 + i * ASZ);
        #pragma unroll
        for (int q = 0; q < 4; ++q) {
            float4 v = bp[q];
            wb[q*4+0] = v.x; wb[q*4+1] = v.y; wb[q*4+2] = v.z; wb[q*4+3] = v.w;
        }
        #pragma unroll
        for (int s4 = 0; s4 < 4; ++s4) {
            float t = 0.f;
            #pragma unroll
            for (int a = 0; a < ASZ; ++a) t += wb[a] * ur[s4][a];
            acc[s4] = t;
        }
    }

    for (int h = 0; h < HSZ; ++h) {
        float w[ASZ];
        const float4* wp = (const float4*)(Wb2 + (size_t)h * (SSZ * ASZ) + i * ASZ);
        #pragma unroll
        for (int q = 0; q < 4; ++q) {
            float4 v = wp[q];
            w[q*4+0] = v.x; w[q*4+1] = v.y; w[q*4+2] = v.z; w[q*4+3] = v.w;
        }
        #pragma unroll
        for (int s4 = 0; s4 < 4; ++s4) {
            float t = 0.f;
            #pragma unroll
            for (int a = 0; a < ASZ; ++a) t += w[a] * ur[s4][a];
            acc[s4] += hb_lds[sg * 4 + s4][h] * t;
        }
    }

    #pragma unroll
    for (int s4 = 0; s4 < 4; ++s4)
        out[(s0 + sg * 4 + s4) * SSZ + i] = acc[s4];
}

// ---------------------------------------------------------------------------
// Kernel 2: r10-exact MFMA rollout (VALU ha + 3-way tiled-W global_load_lds
// staging, 2 bufs, vmcnt(6) ladder, serial wait_tag) + r14 arrival gate:
// tid0 polls ONE counter line, then tagged reads (~1 round); producer does
// tagged stores -> vmcnt(0) -> one atomicAdd. Tags = correctness truth.
// NO per-step per-lane global fragment loads anywhere (the r11-r14 trap).
// ---------------------------------------------------------------------------
__global__ __launch_bounds__(512, 1) void ssm_mfma(
    const float* __restrict__ x0,
    const float* __restrict__ Wa1, const float* __restrict__ ba1,
    const ushort_t* __restrict__ wth, const ushort_t* __restrict__ wtm,
    const ushort_t* __restrict__ wtl, const float* __restrict__ ba2,
    float* __restrict__ out, u64* __restrict__ xbuf,
    unsigned* __restrict__ cnt)
{
    extern __shared__ char smem[];
    float* x_lds = (float*)(smem + MF_X_OFF);
    float* red   = (float*)(smem + MF_RED_OFF);
    char*  haH   = smem + MF_HAH_OFF;     // [16][520] u16, row 1040B
    char*  haM   = smem + MF_HAM_OFF;
    char*  haL   = smem + MF_HAL_OFF;
    char*  wch   = smem + MF_WCH_OFF;     // 2 bufs x {H,M,L 16KB each}

    const int tid  = threadIdx.x;
    const int lane = tid & 63;
    const int wv   = tid >> 6;
    const int l15  = lane & 15, lg = lane >> 4;
    const int bt = blockIdx.x >> 4, ct = blockIdx.x & 15;
    const long bbase = (long)bt * 16;

    const size_t wtile = (size_t)((ct * 8 + wv) * 16) * 1024 + (size_t)lane * 8;

    const float ba2v0 = ba2[ct * 256 + 32 * wv + l15];
    const float ba2v1 = ba2[ct * 256 + 32 * wv + 16 + l15];
    const int jt  = 32 * (wv & 1) + l15;
    const int s_e = l15, q_e = lg;

    const int abyte  = l15 * 1040 + lg * 16;
    const int b0byte = wv * 2048 + lg * 512 + l15 * 16;
    const int b1byte = b0byte + 256;

    unsigned* mycnt = cnt + bt * TSZ;

    for (int t = 0; t < TSZ; ++t) {
        // ---- prestage chunk 0 -> buf 0 (lands under gate/ha) ----
        {
            char* db = wch + wv * 2048;
            const ushort_t* gH = wth + wtile;
            const ushort_t* gM = wtm + wtile;
            const ushort_t* gL = wtl + wtile;
            stage16(gH, db);           stage16(gH + 512, db + 1024);
            stage16(gM, db + 16384);   stage16(gM + 512, db + 16384 + 1024);
            stage16(gL, db + 32768);   stage16(gL + 512, db + 32768 + 1024);
        }

        // ---- bu (wave0; cached load of bytes only bu_kernel wrote) ----
        float bu_v = 0.f;
        if (wv == 0)
            bu_v = out[((bbase + s_e) * TSZ + t) * SSZ + (ct * 4 + q_e)];

        // ---- arrival gate: ONE line polled by tid0, backoff sleep ----
        if (t > 0) {
            if (tid == 0) {
                while (__hip_atomic_load(&mycnt[t - 1], __ATOMIC_RELAXED,
                                         __HIP_MEMORY_SCOPE_AGENT) < 16u)
                    __builtin_amdgcn_s_sleep(2);
            }
            __syncthreads();
        }

        // ---- obtain x_{t-1} (first 4 waves; tagged reads, ~1 round) ----
        if (tid < 256) {
            const int sx = tid >> 4, jx = (tid & 15) * 4;
            float xv0, xv1, xv2, xv3;
            if (t > 0) {
                const u64* xs = xbuf + (size_t)((t - 1) & 3) * (BSZ * SSZ)
                              + (bbase + sx) * SSZ + jx;
                xv0 = wait_tag(xs + 0, (unsigned)t);
                xv1 = wait_tag(xs + 1, (unsigned)t);
                xv2 = wait_tag(xs + 2, (unsigned)t);
                xv3 = wait_tag(xs + 3, (unsigned)t);
            } else {
                const f32x4 x4 = *(const f32x4*)(x0 + (bbase + sx) * SSZ + jx);
                xv0 = x4.x; xv1 = x4.y; xv2 = x4.z; xv3 = x4.w;
            }
            x_lds[sx * SSZ + jx + 0] = xv0;
            x_lds[sx * SSZ + jx + 1] = xv1;
            x_lds[sx * SSZ + jx + 2] = xv2;
            x_lds[sx * SSZ + jx + 3] = xv3;
        }
        __syncthreads();

        // ---- ha = tanh(x @ Wa1 + ba1) -> 3-way bf16 split in LDS [s][h] ----
        {
            const int h0 = tid;
            float ar[16];
            const float b0 = ba1[h0];
            #pragma unroll
            for (int s = 0; s < 16; ++s) ar[s] = b0;
            #pragma unroll 4
            for (int jb = 0; jb < 16; ++jb) {
                float w0[4];
                #pragma unroll
                for (int q = 0; q < 4; ++q)
                    w0[q] = Wa1[(jb * 4 + q) * HSZ + h0];
                #pragma unroll
                for (int s = 0; s < 16; ++s) {
                    const f32x4 xr = *(const f32x4*)&x_lds[s * SSZ + jb * 4];
                    ar[s] += xr.x*w0[0] + xr.y*w0[1] + xr.z*w0[2] + xr.w*w0[3];
                }
            }
            #pragma unroll
            for (int s = 0; s < 16; ++s) {
                const float v = tanhf(ar[s]);
                const ushort_t H = f32_to_bf16(v);
                const float r1 = v - bf16_to_f32(H);
                const ushort_t M = f32_to_bf16(r1);
                const ushort_t L = f32_to_bf16(r1 - bf16_to_f32(M));
                ((ushort_t*)(haH + s * 1040))[h0] = H;
                ((ushort_t*)(haM + s * 1040))[h0] = M;
                ((ushort_t*)(haL + s * 1040))[h0] = L;
            }
        }
        __syncthreads();   // ha complete (cross-wave h ownership)

        // ---- MFMA G-GEMM: 16 K-chunks, 6-pass 3x3 split, vmcnt(6) ladder ----
        f32x4 acc0 = {0.f, 0.f, 0.f, 0.f};
        f32x4 acc1 = {0.f, 0.f, 0.f, 0.f};
        #pragma unroll
        for (int k = 0; k < 16; ++k) {
            if (k + 1 < 16) {
                char* db = wch + ((k + 1) & 1) * 49152 + wv * 2048;
                const ushort_t* gH = wth + wtile + (size_t)(k + 1) * 1024;
                const ushort_t* gM = wtm + wtile + (size_t)(k + 1) * 1024;
                const ushort_t* gL = wtl + wtile + (size_t)(k + 1) * 1024;
                stage16(gH, db);           stage16(gH + 512, db + 1024);
                stage16(gM, db + 16384);   stage16(gM + 512, db + 16384 + 1024);
                stage16(gL, db + 32768);   stage16(gL + 512, db + 32768 + 1024);
                asm volatile("s_waitcnt vmcnt(6)" ::: "memory"); // chunk k landed
            } else {
                asm volatile("s_waitcnt vmcnt(0)" ::: "memory");
            }
            __builtin_amdgcn_sched_barrier(0);

            const char* wb = wch + (k & 1) * 49152;
            const bf16x8 aH  = *(const bf16x8*)(haH + k * 64 + abyte);
            const bf16x8 aM  = *(const bf16x8*)(haM + k * 64 + abyte);
            const bf16x8 aL  = *(const bf16x8*)(haL + k * 64 + abyte);
            const bf16x8 b0H = *(const bf16x8*)(wb + b0byte);
            const bf16x8 b0M = *(const bf16x8*)(wb + 16384 + b0byte);
            const bf16x8 b0L = *(const bf16x8*)(wb + 32768 + b0byte);
            const bf16x8 b1H = *(const bf16x8*)(wb + b1byte);
            const bf16x8 b1M = *(const bf16x8*)(wb + 16384 + b1byte);
            const bf16x8 b1L = *(const bf16x8*)(wb + 32768 + b1byte);

            // small-first accumulation (identical order to r9/r10)
            acc0 = __builtin_amdgcn_mfma_f32_16x16x32_bf16(aL, b0H, acc0, 0, 0, 0);
            acc0 = __builtin_amdgcn_mfma_f32_16x16x32_bf16(aM, b0M, acc0, 0, 0, 0);
            acc0 = __builtin_amdgcn_mfma_f32_16x16x32_bf16(aH, b0L, acc0, 0, 0, 0);
            acc0 = __builtin_amdgcn_mfma_f32_16x16x32_bf16(aM, b0H, acc0, 0, 0, 0);
            acc0 = __builtin_amdgcn_mfma_f32_16x16x32_bf16(aH, b0M, acc0, 0, 0, 0);
            acc0 = __builtin_amdgcn_mfma_f32_16x16x32_bf16(aH, b0H, acc0, 0, 0, 0);
            acc1 = __builtin_amdgcn_mfma_f32_16x16x32_bf16(aL, b1H, acc1, 0, 0, 0);
            acc1 = __builtin_amdgcn_mfma_f32_16x16x32_bf16(aM, b1M, acc1, 0, 0, 0);
            acc1 = __builtin_amdgcn_mfma_f32_16x16x32_bf16(aH, b1L, acc1, 0, 0, 0);
            acc1 = __builtin_amdgcn_mfma_f32_16x16x32_bf16(aM, b1H, acc1, 0, 0, 0);
            acc1 = __builtin_amdgcn_mfma_f32_16x16x32_bf16(aH, b1M, acc1, 0, 0, 0);
            acc1 = __builtin_amdgcn_mfma_f32_16x16x32_bf16(aH, b1H, acc1, 0, 0, 0);
        }

        // ---- epilogue: +ba2, x-contract, reduce 16 lanes, publish ----
        float part[4];
        #pragma unroll
        for (int r = 0; r < 4; ++r) {
            const int s = lg * 4 + r;                    // C row (m89 layout)
            part[r] = (acc0[r] + ba2v0) * x_lds[s * SSZ + jt]
                    + (acc1[r] + ba2v1) * x_lds[s * SSZ + jt + 16];
            part[r] += __shfl_xor(part[r], 1);
            part[r] += __shfl_xor(part[r], 2);
            part[r] += __shfl_xor(part[r], 4);
            part[r] += __shfl_xor(part[r], 8);
        }
        if (l15 == 0) {
            #pragma unroll
            for (int r = 0; r < 4; ++r)
                red[wv * 16 + lg * 4 + r] = part[r];
        }
        __syncthreads();

        if (wv == 0) {
            const long b = bbase + s_e;
            const int  i = ct * 4 + q_e;
            const float xn = red[(2 * q_e) * 16 + s_e]
                           + red[(2 * q_e + 1) * 16 + s_e] + bu_v;
            out[(b * TSZ + t) * SSZ + i] = xn;           // final (write-once)
            const u64 w = ((u64)(unsigned)(t + 1) << 32)
                        | (u64)__float_as_uint(xn);
            __hip_atomic_store(xbuf + (size_t)(t & 3) * (BSZ * SSZ) + b * SSZ + i,
                               w, __ATOMIC_RELAXED, __HIP_MEMORY_SCOPE_AGENT);
            // arrive: own stores drained, then ONE counter add per WG
            asm volatile("s_waitcnt vmcnt(0)" ::: "memory");
            if (lane == 0)
                __hip_atomic_fetch_add(&mycnt[t], 1u, __ATOMIC_RELAXED,
                                       __HIP_MEMORY_SCOPE_AGENT);
        }
    }
}

// ---------------------------------------------------------------------------
// Kernel 2 (FALLBACK, round-7 f32 path, used when ws_size < WS_NEEDED)
// ---------------------------------------------------------------------------
__global__ __launch_bounds__(512, 1) void ssm_f32(
    const float* __restrict__ x0,
    const float* __restrict__ Wa1, const float* __restrict__ ba1,
    const float* __restrict__ Wa2, const float* __restrict__ ba2,
    float* __restrict__ out, u64* __restrict__ xbuf)
{
    extern __shared__ float smemf[];
    float* x_lds = smemf + X_OFF;
    float* ha_t  = smemf + HA_OFF;
    float* wchf  = smemf + W_OFF;
    float* redf  = smemf + RED_OFF;

    const int tid  = threadIdx.x;
    const int lane = tid & 63;
    const int wv   = tid >> 6;
    const int bt = blockIdx.x >> 4;
    const int ct = blockIdx.x & 15;
    const long bbase = (long)bt * 16;

    const int c0 = ct * 256 + lane * 4;
    const f32x4 ba2r = *(const f32x4*)(ba2 + c0);
    const int j0 = (lane & 15) * 4;
    const int s_e = lane & 15, il_e = lane >> 4;

    for (int t = 0; t < TSZ; ++t) {
        #pragma unroll
        for (int it = 0; it < 4; ++it)
            stage16(Wa2 + (size_t)(wv * 4 + it) * 4096 + c0,
                    wchf + (0 * 32 + wv * 4 + it) * 256);
        #pragma unroll
        for (int it = 0; it < 4; ++it)
            stage16(Wa2 + (size_t)(32 + wv * 4 + it) * 4096 + c0,
                    wchf + (1 * 32 + wv * 4 + it) * 256);

        float bu_v = 0.f;
        if (wv == 0)
            bu_v = out[((bbase + s_e) * TSZ + t) * SSZ + (ct * 4 + il_e)];

        if (tid < 256) {
            const int sx = tid >> 4, jx = (tid & 15) * 4;
            float xv0, xv1, xv2, xv3;
            if (t > 0) {
                const u64* xs = xbuf + (size_t)((t - 1) & 3) * (BSZ * SSZ)
                              + (bbase + sx) * SSZ + jx;
                xv0 = wait_tag(xs + 0, (unsigned)t);
                xv1 = wait_tag(xs + 1, (unsigned)t);
                xv2 = wait_tag(xs + 2, (unsigned)t);
                xv3 = wait_tag(xs + 3, (unsigned)t);
            } else {
                const f32x4 x4 = *(const f32x4*)(x0 + (bbase + sx) * SSZ + jx);
                xv0 = x4.x; xv1 = x4.y; xv2 = x4.z; xv3 = x4.w;
            }
            x_lds[sx * SSZ + jx + 0] = xv0;
            x_lds[sx * SSZ + jx + 1] = xv1;
            x_lds[sx * SSZ + jx + 2] = xv2;
            x_lds[sx * SSZ + jx + 3] = xv3;
        }
        __syncthreads();

        {
            const int h0 = tid;
            float ar[16];
            const float b0 = ba1[h0];
            #pragma unroll
            for (int s = 0; s < 16; ++s) ar[s] = b0;
            #pragma unroll 4
            for (int jb = 0; jb < 16; ++jb) {
                float w0[4];
                #pragma unroll
                for (int q = 0; q < 4; ++q)
                    w0[q] = Wa1[(jb * 4 + q) * HSZ + h0];
                #pragma unroll
                for (int s = 0; s < 16; ++s) {
                    const f32x4 xr = *(const f32x4*)&x_lds[s * SSZ + jb * 4];
                    ar[s] += xr.x*w0[0] + xr.y*w0[1] + xr.z*w0[2] + xr.w*w0[3];
                }
            }
            #pragma unroll
            for (int s = 0; s < 16; ++s) ar[s] = tanhf(ar[s]);
            #pragma unroll
            for (int q = 0; q < 4; ++q) {
                f32x4 v0;
                v0.x=ar[q*4+0]; v0.y=ar[q*4+1]; v0.z=ar[q*4+2]; v0.w=ar[q*4+3];
                *(f32x4*)&ha_t[h0 * HA_STR + q * 4] = v0;
            }
        }
        __syncthreads();

        f32x4 acc[16];
        {
            const f32x4 zero = {0.f, 0.f, 0.f, 0.f};
            const f32x4 ini = (wv == 0) ? ba2r : zero;
            #pragma unroll
            for (int s = 0; s < 16; ++s) acc[s] = ini;
        }
        for (int k = 0; k < NCH; ++k) {
            if (k + 2 < NCH) {
                #pragma unroll
                for (int it = 0; it < 4; ++it)
                    stage16(Wa2 + (size_t)((k + 2) * 32 + wv * 4 + it) * 4096 + c0,
                            wchf + (((k + 2) % 3) * 32 + wv * 4 + it) * 256);
                asm volatile("s_waitcnt vmcnt(8)" ::: "memory");
            } else if (k + 1 < NCH) {
                asm volatile("s_waitcnt vmcnt(4)" ::: "memory");
            } else {
                asm volatile("s_waitcnt vmcnt(0)" ::: "memory");
            }
            __builtin_amdgcn_sched_barrier(0);

            const float* wb = wchf + (k % 3) * 8192 + (wv * 4) * 256;
            const float* hb = ha_t + (size_t)(k * 32 + wv * 4) * HA_STR;
            #pragma unroll
            for (int rr = 0; rr < 4; ++rr) {
                const f32x4 w4 = *(const f32x4*)(wb + rr * 256 + lane * 4);
                const f32x4 h0 = *(const f32x4*)(hb + rr * HA_STR + 0);
                const f32x4 h1 = *(const f32x4*)(hb + rr * HA_STR + 4);
                const f32x4 h2 = *(const f32x4*)(hb + rr * HA_STR + 8);
                const f32x4 h3 = *(const f32x4*)(hb + rr * HA_STR + 12);
                acc[0]  += h0.x * w4; acc[1]  += h0.y * w4;
                acc[2]  += h0.z * w4; acc[3]  += h0.w * w4;
                acc[4]  += h1.x * w4; acc[5]  += h1.y * w4;
                acc[6]  += h1.z * w4; acc[7]  += h1.w * w4;
                acc[8]  += h2.x * w4; acc[9]  += h2.y * w4;
                acc[10] += h2.z * w4; acc[11] += h2.w * w4;
                acc[12] += h3.x * w4; acc[13] += h3.y * w4;
                acc[14] += h3.z * w4; acc[15] += h3.w * w4;
            }
        }

        float part[16];
        #pragma unroll
        for (int s = 0; s < 16; ++s) {
            const f32x4 xr = *(const f32x4*)&x_lds[s * SSZ + j0];
            part[s] = acc[s].x*xr.x + acc[s].y*xr.y + acc[s].z*xr.z + acc[s].w*xr.w;
        }
        #pragma unroll
        for (int s = 0; s < 16; ++s) {
            part[s] += __shfl_xor(part[s], 1);
            part[s] += __shfl_xor(part[s], 2);
            part[s] += __shfl_xor(part[s], 4);
            part[s] += __shfl_xor(part[s], 8);
        }
        if ((lane & 15) == 0) {
            const int il = lane >> 4;
            #pragma unroll
            for (int s = 0; s < 16; ++s)
                redf[(wv * 4 + il) * 16 + s] = part[s];
        }
        __syncthreads();

        if (wv == 0) {
            const long b = bbase + s_e;
            const int  i = ct * 4 + il_e;
            float r = 0.f;
            #pragma unroll
            for (int w8 = 0; w8 < 8; ++w8)
                r += redf[(w8 * 4 + il_e) * 16 + s_e];
            const float xn = r + bu_v;
            out[(b * TSZ + t) * SSZ + i] = xn;
            const u64 w = ((u64)(unsigned)(t + 1) << 32)
                        | (u64)__float_as_uint(xn);
            __hip_atomic_store(xbuf + (size_t)(t & 3) * (BSZ * SSZ) + b * SSZ + i,
                               w, __ATOMIC_RELAXED, __HIP_MEMORY_SCOPE_AGENT);
        }
    }
}

// ---------------------------------------------------------------------------
extern "C" void kernel_launch(void* const* d_in, const int* in_sizes, int n_in,
                              void* d_out, int out_size, void* d_ws, size_t ws_size,
                              hipStream_t stream) {
    const float* x0  = (const float*)d_in[0];
    const float* us  = (const float*)d_in[1];
    const float* Wa1 = (const float*)d_in[2];
    const float* ba1 = (const float*)d_in[3];
    const float* Wa2 = (const float*)d_in[4];
    const float* ba2 = (const float*)d_in[5];
    const float* Wb1 = (const float*)d_in[6];
    const float* bb1 = (const float*)d_in[7];
    const float* Wb2 = (const float*)d_in[8];
    const float* bb2 = (const float*)d_in[9];
    float* out = (float*)d_out;

    u64* xbuf = (u64*)d_ws;                                   // 512KB
    unsigned* cnt = (unsigned*)((char*)d_ws + XBUF_BYTES);    // 16KB
    // zero tags + counters (captured => runs every replay; replay-safe)
    hipMemsetAsync(d_ws, 0, XBUF_BYTES + CNT_BYTES, stream);

    // Phase 1: bu -> d_out
    hipLaunchKernelGGL(bu_kernel, dim3((BSZ * TSZ) / 16), dim3(256), 0, stream,
                       us, Wb1, bb1, Wb2, bb2, out);

    if (ws_size >= WS_NEEDED) {
        ushort_t* wth = (ushort_t*)((char*)d_ws + XBUF_BYTES + CNT_BYTES);
        ushort_t* wtm = wth + WT_ELEMS;
        ushort_t* wtl = wtm + WT_ELEMS;
        // Phase 0: transpose + 3-way split Wa2 into tiled layout
        hipLaunchKernelGGL(wsplit_kernel, dim3(512), dim3(256), 0, stream,
                           Wa2, wth, wtm, wtl);
        (void)hipFuncSetAttribute((const void*)ssm_mfma,
                                  hipFuncAttributeMaxDynamicSharedMemorySize, MF_SMEM);
        void* args[] = {(void*)&x0, (void*)&Wa1, (void*)&ba1,
                        (void*)&wth, (void*)&wtm, (void*)&wtl, (void*)&ba2,
                        (void*)&out, (void*)&xbuf, (void*)&cnt};
        hipLaunchCooperativeKernel((const void*)ssm_mfma, dim3(256), dim3(512),
                                   args, MF_SMEM, stream);
    } else {
        (void)hipFuncSetAttribute((const void*)ssm_f32,
                                  hipFuncAttributeMaxDynamicSharedMemorySize, SMEM_BYTES);
        void* args[] = {(void*)&x0, (void*)&Wa1, (void*)&ba1,
                        (void*)&Wa2, (void*)&ba2, (void*)&out, (void*)&xbuf};
        hipLaunchCooperativeKernel((const void*)ssm_f32, dim3(256), dim3(512),
                                   args, SMEM_BYTES, stream);
    }
}